// Round 4
// baseline (9.858 us; speedup 1.0000x reference)
//
#include <hip/hip_runtime.h>

// Closed form of the QLayer circuit (verified r1-r3, absmax <= 2e-3):
//   c_i = cos(x_i + theta_i); z[0] = c1..c7, z[w] = c0..cw (w>=1).
// Per token: G = z z^T / sqrt(8); attn = softmax rows; o = attn @ z;
//            y = o @ W^T + b.
//
// R4 (latency-focused): 16 tokens / 128 threads / block -> 1024 blocks
//   (4 blocks/CU, 4 independent barrier domains).
//   W is NOT staged in LDS: each phase-3 lane loads its 32 W floats
//   global->register at kernel top (hidden under phases 1-2), converts to
//   bf16 in-register at MFMA time. Only z (f32) and o (bf16) touch LDS.
//   Softmax max-pass dropped (scores in [-2.83,2.83] -> exp <= 17, safe).
// Fragment maps (m89-verified, same as passing R3):
//   A: lane l -> A[m=l&15][k=(l>>4)*8+i]
//   B: lane l -> B[k=(l>>4)*8+i][n=l&15]
//   C: lane l, reg r -> [m=(l>>4)*4+r][n=l&15]

#define TOK_PER_BLK 16

typedef __attribute__((ext_vector_type(8))) short short8;
typedef __attribute__((ext_vector_type(4))) float f32x4;

__device__ inline unsigned short f2bf(float f) {
    unsigned u = __float_as_uint(f);
    u += 0x7FFF + ((u >> 16) & 1);          // RNE
    return (unsigned short)(u >> 16);
}

__device__ inline short8 pack_bf16x8(float4 a, float4 b) {
    short8 r;
    r[0] = (short)f2bf(a.x); r[1] = (short)f2bf(a.y);
    r[2] = (short)f2bf(a.z); r[3] = (short)f2bf(a.w);
    r[4] = (short)f2bf(b.x); r[5] = (short)f2bf(b.y);
    r[6] = (short)f2bf(b.z); r[7] = (short)f2bf(b.w);
    return r;
}

__global__ __launch_bounds__(128, 2)
void mhaq_fused4(const float* __restrict__ x,
                 const float* __restrict__ theta,
                 const float* __restrict__ W,
                 const float* __restrict__ bias,
                 float* __restrict__ out,
                 int n_tokens)
{
    __shared__ __align__(16) float          zs[TOK_PER_BLK * 68]; // f32, pad 4
    __shared__ __align__(16) unsigned short os[TOK_PER_BLK * 72]; // bf16, pad 8

    const int tid  = threadIdx.x;
    const int lane = tid & 63;
    const int wave = tid >> 6;          // 0..1
    const int lr   = lane & 15;
    const int lg   = lane >> 4;         // 0..3
    const int blockbase = blockIdx.x * TOK_PER_BLK;

    // ---- issue W + bias loads NOW; consumed after 2nd barrier (phase 3) ----
    float4 wf[2][2][2];                 // [nt][kt][half]
    float  bj[2];
    {
        const float4* __restrict__ Wv = reinterpret_cast<const float4*>(W);
        #pragma unroll
        for (int nt = 0; nt < 2; ++nt) {
            int j = wave * 32 + nt * 16 + lr;
            bj[nt] = bias[j];
            #pragma unroll
            for (int kt = 0; kt < 2; ++kt) {
                int fidx = (j * 64 + kt * 32 + lg * 8) >> 2;
                wf[nt][kt][0] = Wv[fidx];
                wf[nt][kt][1] = Wv[fidx + 1];
            }
        }
    }

    // ---- phase 1: z for own (token, head) ----
    const int tl = tid >> 3;            // 0..15
    const int g  = tid & 7;
    const int token = blockbase + tl;
    const bool valid = token < n_tokens;
    float zh[8];
    {
        float4 a  = make_float4(0.f, 0.f, 0.f, 0.f);
        float4 b4 = make_float4(0.f, 0.f, 0.f, 0.f);
        if (valid) {
            const float4* __restrict__ xp =
                reinterpret_cast<const float4*>(x) + (size_t)token * 16 + g * 2;
            a = xp[0]; b4 = xp[1];
        }
        float c0 = __cosf(a.x  + theta[0]);
        float c1 = __cosf(a.y  + theta[1]);
        float c2 = __cosf(a.z  + theta[2]);
        float c3 = __cosf(a.w  + theta[3]);
        float c4 = __cosf(b4.x + theta[4]);
        float c5 = __cosf(b4.y + theta[5]);
        float c6 = __cosf(b4.z + theta[6]);
        float c7 = __cosf(b4.w + theta[7]);
        float p1 = c0 * c1;
        float p2 = p1 * c2;
        float p3 = p2 * c3;
        float p4 = p3 * c4;
        float p5 = p4 * c5;
        float p6 = p5 * c6;
        float p7 = p6 * c7;
        float s6 = c6 * c7;
        float s5 = c5 * s6;
        float s4 = c4 * s5;
        float s3 = c3 * s4;
        float s2 = c2 * s3;
        float s1 = c1 * s2;     // c1*...*c7
        zh[0] = s1; zh[1] = p1; zh[2] = p2; zh[3] = p3;
        zh[4] = p4; zh[5] = p5; zh[6] = p6; zh[7] = p7;

        float4* z4 = reinterpret_cast<float4*>(zs + tl * 68 + g * 8);
        z4[0] = make_float4(zh[0], zh[1], zh[2], zh[3]);
        z4[1] = make_float4(zh[4], zh[5], zh[6], zh[7]);
    }
    __syncthreads();

    // ---- phase 2: attention head g; o -> bf16 LDS ----
    {
        __align__(16) float zf[64];
        const float* zrow = zs + tl * 68;
        #pragma unroll
        for (int k4 = 0; k4 < 16; ++k4)
            *reinterpret_cast<float4*>(&zf[4 * k4]) =
                *reinterpret_cast<const float4*>(&zrow[4 * k4]);

        const float scale = 0.35355339059327373f; // 1/sqrt(8)
        float sc[8];
        #pragma unroll
        for (int t = 0; t < 8; ++t) {
            float s = 0.f;
            #pragma unroll
            for (int d = 0; d < 8; ++d)
                s = fmaf(zh[d], zf[t * 8 + d], s);
            sc[t] = __expf(s * scale);   // s*scale in [-2.83,2.83]; no max pass
        }
        float sum = sc[0] + sc[1] + sc[2] + sc[3]
                  + sc[4] + sc[5] + sc[6] + sc[7];
        float inv = 1.0f / sum;

        unsigned short oh[8];
        #pragma unroll
        for (int d = 0; d < 8; ++d) {
            float acc = 0.f;
            #pragma unroll
            for (int t = 0; t < 8; ++t)
                acc = fmaf(sc[t], zf[t * 8 + d], acc);
            oh[d] = f2bf(acc * inv);
        }
        ushort4* o4 = reinterpret_cast<ushort4*>(&os[tl * 72 + g * 8]);
        o4[0] = make_ushort4(oh[0], oh[1], oh[2], oh[3]);
        o4[1] = make_ushort4(oh[4], oh[5], oh[6], oh[7]);
    }
    __syncthreads();

    // ---- phase 3: y = o @ W^T + b via MFMA; W frags from registers ----
    {
        short8 afrag[2];
        #pragma unroll
        for (int kt = 0; kt < 2; ++kt)
            afrag[kt] = *reinterpret_cast<const short8*>(
                &os[lr * 72 + kt * 32 + lg * 8]);

        #pragma unroll
        for (int nt = 0; nt < 2; ++nt) {
            int j = wave * 32 + nt * 16 + lr;
            f32x4 acc = {bj[nt], bj[nt], bj[nt], bj[nt]};
            #pragma unroll
            for (int kt = 0; kt < 2; ++kt) {
                short8 bfrag = pack_bf16x8(wf[nt][kt][0], wf[nt][kt][1]);
                acc = __builtin_amdgcn_mfma_f32_16x16x32_bf16(
                    afrag[kt], bfrag, acc, 0, 0, 0);
            }
            #pragma unroll
            for (int r = 0; r < 4; ++r) {
                int trow = blockbase + lg * 4 + r;
                if (trow < n_tokens)
                    out[(size_t)trow * 64 + j] = acc[r];
            }
        }
    }
}

extern "C" void kernel_launch(void* const* d_in, const int* in_sizes, int n_in,
                              void* d_out, int out_size, void* d_ws, size_t ws_size,
                              hipStream_t stream)
{
    const float* x     = (const float*)d_in[0];
    const float* theta = (const float*)d_in[1];
    const float* W     = (const float*)d_in[2];
    const float* b     = (const float*)d_in[3];
    float* out         = (float*)d_out;

    const int n_tokens = in_sizes[0] / 64;                            // 16384
    const int blocks   = (n_tokens + TOK_PER_BLK - 1) / TOK_PER_BLK;  // 1024
    mhaq_fused4<<<blocks, 128, 0, stream>>>(x, theta, W, b, out, n_tokens);
}

// Round 5
// 9.764 us; speedup vs baseline: 1.0097x; 1.0097x over previous
//
#include <hip/hip_runtime.h>

// Closed form of the QLayer circuit (verified r1-r4, absmax <= 2e-3):
//   c_i = cos(x_i + theta_i); z[0] = c1..c7, z[w] = c0..cw (w>=1).
// Per token: G = z z^T / sqrt(8); attn = softmax rows (max-pass dropped,
//   scores in [-2.83,2.83]); o = attn @ z; y = o @ W^T + b.
//
// R5: (a) x load issued BEFORE W loads — consuming x now waits vmcnt(N>0),
//     not vmcnt(0); W prefetch actually stays in flight until phase 3.
//     (b) 16 threads/token -> 4096 waves (4/SIMD) and halved per-thread
//     phase-2 work: thread (token, s) owns head h=s>>1, half=s&1.
//     Scores for t in [half*4, half*4+4), partner exchange via shfl_xor(1).
// Fragment maps (m89-verified, same as passing R3/R4):
//   A: lane l -> A[m=l&15][k=(l>>4)*8+i]
//   B: lane l -> B[k=(l>>4)*8+i][n=l&15]
//   C: lane l, reg r -> [m=(l>>4)*4+r][n=l&15]

#define TOK_PER_BLK 16

typedef __attribute__((ext_vector_type(8))) short short8;
typedef __attribute__((ext_vector_type(4))) float f32x4;

__device__ inline unsigned short f2bf(float f) {
    unsigned u = __float_as_uint(f);
    u += 0x7FFF + ((u >> 16) & 1);          // RNE
    return (unsigned short)(u >> 16);
}

__device__ inline short8 pack_bf16x8(float4 a, float4 b) {
    short8 r;
    r[0] = (short)f2bf(a.x); r[1] = (short)f2bf(a.y);
    r[2] = (short)f2bf(a.z); r[3] = (short)f2bf(a.w);
    r[4] = (short)f2bf(b.x); r[5] = (short)f2bf(b.y);
    r[6] = (short)f2bf(b.z); r[7] = (short)f2bf(b.w);
    return r;
}

__global__ __launch_bounds__(256, 4)
void mhaq_fused5(const float* __restrict__ x,
                 const float* __restrict__ theta,
                 const float* __restrict__ W,
                 const float* __restrict__ bias,
                 float* __restrict__ out,
                 int n_tokens)
{
    __shared__ __align__(16) float          zs[TOK_PER_BLK * 68]; // f32, pad 4
    __shared__ __align__(16) unsigned short os[TOK_PER_BLK * 72]; // bf16, pad 8

    const int tid  = threadIdx.x;
    const int tl   = tid >> 4;          // token within block, 0..15
    const int s    = tid & 15;
    const int h    = s >> 1;            // head this thread attends
    const int half = s & 1;             // t-range / d-range half
    const int blockbase = blockIdx.x * TOK_PER_BLK;
    const int token = blockbase + tl;
    const bool zrole = (s < 8);

    // ---- x load FIRST (phase-1 critical path) ----
    float4 xa = make_float4(0.f, 0.f, 0.f, 0.f);
    float4 xb = make_float4(0.f, 0.f, 0.f, 0.f);
    if (zrole && token < n_tokens) {
        const float4* __restrict__ xp =
            reinterpret_cast<const float4*>(x) + (size_t)token * 16 + s * 2;
        xa = xp[0]; xb = xp[1];
    }

    // ---- W + bias prefetch (consumed in phase 3, after 2 barriers) ----
    const int lane = tid & 63;
    const int wave = tid >> 6;          // 0..3 -> j-quarter
    const int lr   = lane & 15;
    const int lg   = lane >> 4;         // 0..3
    const int j    = wave * 16 + lr;
    float4 wf[2][2];                    // [kt][half8]
    float  bj = bias[j];
    {
        const float4* __restrict__ Wv = reinterpret_cast<const float4*>(W);
        #pragma unroll
        for (int kt = 0; kt < 2; ++kt) {
            int fidx = (j * 64 + kt * 32 + lg * 8) >> 2;
            wf[kt][0] = Wv[fidx];
            wf[kt][1] = Wv[fidx + 1];
        }
    }

    // ---- phase 1: threads s<8 compute z for head s ----
    if (zrole) {
        float c0 = __cosf(xa.x + theta[0]);
        float c1 = __cosf(xa.y + theta[1]);
        float c2 = __cosf(xa.z + theta[2]);
        float c3 = __cosf(xa.w + theta[3]);
        float c4 = __cosf(xb.x + theta[4]);
        float c5 = __cosf(xb.y + theta[5]);
        float c6 = __cosf(xb.z + theta[6]);
        float c7 = __cosf(xb.w + theta[7]);
        float p1 = c0 * c1;
        float p2 = p1 * c2;
        float p3 = p2 * c3;
        float p4 = p3 * c4;
        float p5 = p4 * c5;
        float p6 = p5 * c6;
        float p7 = p6 * c7;
        float s6 = c6 * c7;
        float s5 = c5 * s6;
        float s4 = c4 * s5;
        float s3 = c3 * s4;
        float s2 = c2 * s3;
        float s1 = c1 * s2;             // c1*...*c7
        float4* z4 = reinterpret_cast<float4*>(zs + tl * 68 + s * 8);
        z4[0] = make_float4(s1, p1, p2, p3);
        z4[1] = make_float4(p4, p5, p6, p7);
    }
    __syncthreads();

    // ---- phase 2: head h, halves of t and d; o -> bf16 LDS ----
    {
        const float* zrow = zs + tl * 68;
        float zh[8];
        *reinterpret_cast<float4*>(&zh[0]) =
            *reinterpret_cast<const float4*>(&zrow[h * 8]);
        *reinterpret_cast<float4*>(&zh[4]) =
            *reinterpret_cast<const float4*>(&zrow[h * 8 + 4]);

        // score rows: t = half*4 .. half*4+3 (contiguous 32 floats)
        float zt[32];
        #pragma unroll
        for (int i = 0; i < 8; ++i)
            *reinterpret_cast<float4*>(&zt[i * 4]) =
                *reinterpret_cast<const float4*>(&zrow[half * 32 + i * 4]);

        const float scale = 0.35355339059327373f;  // 1/sqrt(8)
        float e[4];
        float psum = 0.f;
        #pragma unroll
        for (int tt = 0; tt < 4; ++tt) {
            float sd = 0.f;
            #pragma unroll
            for (int d = 0; d < 8; ++d)
                sd = fmaf(zh[d], zt[tt * 8 + d], sd);
            e[tt] = __expf(sd * scale);
            psum += e[tt];
        }
        float tot = psum + __shfl_xor(psum, 1, 64);
        float inv = 1.0f / tot;

        float ep[4];
        #pragma unroll
        for (int tt = 0; tt < 4; ++tt)
            ep[tt] = __shfl_xor(e[tt], 1, 64);

        // full e in t-order (static indices; per-element select, rule #20)
        float ef[8];
        #pragma unroll
        for (int tt = 0; tt < 4; ++tt) {
            ef[tt]     = half ? ep[tt] : e[tt];
            ef[4 + tt] = half ? e[tt]  : ep[tt];
        }

        // column slice: z[t][half*4 + dd], t=0..7
        float zc[32];
        #pragma unroll
        for (int t = 0; t < 8; ++t)
            *reinterpret_cast<float4*>(&zc[t * 4]) =
                *reinterpret_cast<const float4*>(&zrow[t * 8 + half * 4]);

        unsigned short oh[4];
        #pragma unroll
        for (int dd = 0; dd < 4; ++dd) {
            float acc = 0.f;
            #pragma unroll
            for (int t = 0; t < 8; ++t)
                acc = fmaf(ef[t], zc[t * 4 + dd], acc);
            oh[dd] = f2bf(acc * inv);
        }
        *reinterpret_cast<ushort4*>(&os[tl * 72 + h * 8 + half * 4]) =
            make_ushort4(oh[0], oh[1], oh[2], oh[3]);
    }
    __syncthreads();

    // ---- phase 3: y = o @ W^T + b via MFMA; W frags from registers ----
    {
        short8 afrag[2];
        #pragma unroll
        for (int kt = 0; kt < 2; ++kt)
            afrag[kt] = *reinterpret_cast<const short8*>(
                &os[lr * 72 + kt * 32 + lg * 8]);

        f32x4 acc = {bj, bj, bj, bj};
        #pragma unroll
        for (int kt = 0; kt < 2; ++kt) {
            short8 bfrag = pack_bf16x8(wf[kt][0], wf[kt][1]);
            acc = __builtin_amdgcn_mfma_f32_16x16x32_bf16(
                afrag[kt], bfrag, acc, 0, 0, 0);
        }
        #pragma unroll
        for (int r = 0; r < 4; ++r) {
            int trow = blockbase + lg * 4 + r;
            if (trow < n_tokens)
                out[(size_t)trow * 64 + j] = acc[r];
        }
    }
}

extern "C" void kernel_launch(void* const* d_in, const int* in_sizes, int n_in,
                              void* d_out, int out_size, void* d_ws, size_t ws_size,
                              hipStream_t stream)
{
    const float* x     = (const float*)d_in[0];
    const float* theta = (const float*)d_in[1];
    const float* W     = (const float*)d_in[2];
    const float* b     = (const float*)d_in[3];
    float* out         = (float*)d_out;

    const int n_tokens = in_sizes[0] / 64;                            // 16384
    const int blocks   = (n_tokens + TOK_PER_BLK - 1) / TOK_PER_BLK;  // 1024
    mhaq_fused5<<<blocks, 256, 0, stream>>>(x, theta, W, b, out, n_tokens);
}